// Round 8
// baseline (497.517 us; speedup 1.0000x reference)
//
#include <hip/hip_runtime.h>
#include <hip/hip_bf16.h>
#include <math.h>

#define HIDDEN 2048
#define INTER 1024
#define NEXP 64
#define TOPK 8
#define NTOK 512

#define MT 96                  // M tile rows (6 x 16)
#define ROWB 80                // LDS row stride bytes (32 bf16 = 64B + 16B pad)
#define WROWS 512              // W^T rows per buffer
#define WTB (WROWS * ROWB)     // 40960
#define XOFF WTB
#define BUFB (WTB + MT * ROWB) // 48640 per buffer; x2 = 97280 B LDS
#define AWS_ROWS (NTOK * TOPK + 128)

typedef float floatx4 __attribute__((ext_vector_type(4)));
typedef short shortx8 __attribute__((ext_vector_type(8)));

__device__ __forceinline__ unsigned short bfbits(float f) {
    union { __hip_bfloat16 h; unsigned short u; } c;
    c.h = __float2bfloat16(f);
    return c.u;
}
// pack 4 floats (k-ascending) -> 8B of bf16, k-ascending in memory
__device__ __forceinline__ uint2 pack4(float a, float b, float c, float d) {
    uint2 r;
    r.x = ((unsigned)bfbits(b) << 16) | (unsigned)bfbits(a);
    r.y = ((unsigned)bfbits(d) << 16) | (unsigned)bfbits(c);
    return r;
}

// ---------------- Router + top-8 + softmax + x->bf16 ----------------
__global__ void router_topk_kernel(const float* __restrict__ x,
                                   const float* __restrict__ wr,
                                   int* __restrict__ topk_idx,
                                   float* __restrict__ gates,
                                   __hip_bfloat16* __restrict__ xbf) {
    const int t = blockIdx.x;
    const int lane = threadIdx.x;
    __shared__ float sx[HIDDEN];
    for (int i = lane; i < HIDDEN / 4; i += 64)
        *(float4*)&sx[i * 4] = *(const float4*)(x + (size_t)t * HIDDEN + i * 4);
    __syncthreads();

    // emit bf16 copy of this token's row (replaces separate xcvt kernel)
    for (int i = lane; i < HIDDEN / 4; i += 64) {
        float4 v = *(const float4*)&sx[i * 4];
        ((uint2*)(xbf + (size_t)t * HIDDEN))[i] = pack4(v.x, v.y, v.z, v.w);
    }

    float a0 = 0.f, a1 = 0.f, a2 = 0.f, a3 = 0.f;
#pragma unroll 4
    for (int d = 0; d < HIDDEN; d += 4) {
        a0 = fmaf(sx[d + 0], wr[(d + 0) * NEXP + lane], a0);
        a1 = fmaf(sx[d + 1], wr[(d + 1) * NEXP + lane], a1);
        a2 = fmaf(sx[d + 2], wr[(d + 2) * NEXP + lane], a2);
        a3 = fmaf(sx[d + 3], wr[(d + 3) * NEXP + lane], a3);
    }
    float cur = (a0 + a1) + (a2 + a3);

    float topv[TOPK];
    int topi[TOPK];
#pragma unroll
    for (int k = 0; k < TOPK; ++k) {
        float bv = cur;
        int bi = lane;
#pragma unroll
        for (int off = 32; off > 0; off >>= 1) {
            float ov = __shfl_xor(bv, off, 64);
            int oi = __shfl_xor(bi, off, 64);
            if (ov > bv || (ov == bv && oi < bi)) { bv = ov; bi = oi; }
        }
        topv[k] = bv;
        topi[k] = bi;
        if (lane == bi) cur = -INFINITY;
    }
    if (lane == 0) {
        float m = topv[0];
        float ex[TOPK], s = 0.f;
#pragma unroll
        for (int k = 0; k < TOPK; ++k) { ex[k] = __expf(topv[k] - m); s += ex[k]; }
        float inv = 1.f / s;
#pragma unroll
        for (int k = 0; k < TOPK; ++k) {
            gates[t * TOPK + k] = ex[k] * inv;
            topk_idx[t * TOPK + k] = topi[k];
        }
    }
}

// ---------------- Deterministic bucket build (+done[] reset) ----------------
__global__ void build_buckets_kernel(const int* __restrict__ topk_idx,
                                     const float* __restrict__ gates,
                                     int* __restrict__ bucket_tok,
                                     float* __restrict__ bucket_gate,
                                     int* __restrict__ count,
                                     int* __restrict__ done) {
    const int e = blockIdx.x;
    const int tid = threadIdx.x;
    if (tid == 0) done[e] = 0;     // reset sync flags every call (graph replay)
    __shared__ int scan[256];
    const int t0 = tid * 2;
    int f0 = 0, f1 = 0;
    float g0 = 0.f, g1 = 0.f;
#pragma unroll
    for (int k = 0; k < TOPK; ++k) {
        if (topk_idx[t0 * TOPK + k] == e) { f0 = 1; g0 = gates[t0 * TOPK + k]; }
        if (topk_idx[(t0 + 1) * TOPK + k] == e) { f1 = 1; g1 = gates[(t0 + 1) * TOPK + k]; }
    }
    int s = f0 + f1;
    scan[tid] = s;
    __syncthreads();
    for (int off = 1; off < 256; off <<= 1) {
        int add = (tid >= off) ? scan[tid - off] : 0;
        __syncthreads();
        scan[tid] += add;
        __syncthreads();
    }
    int excl = scan[tid] - s;
    if (f0) { bucket_tok[e * NTOK + excl] = t0; bucket_gate[e * NTOK + excl] = g0; }
    if (f1) { bucket_tok[e * NTOK + excl + f0] = t0 + 1; bucket_gate[e * NTOK + excl + f0] = g1; }
    if (tid == 255) count[e] = scan[255];
}

// ---------------- Fused MoE: gateup -> signal -> wait -> down ----------------
// grid 256 @ 1 block/CU (all blocks resident by construction). Block (e,c):
//   phase 1: gateup chunk c (256 gate + 256 up cols) -> Aws (R7-verified body)
//   signal:  threadfence + atomicAdd(done[e])
//   wait:    tid0 spins until done[e]==4 (siblings {e,e+64,e+128,e+192} share
//            XCD e%8, so Aws producer/consumer is same-XCD-L2 coherent)
//   phase 2: down chunk c (512 out cols) -> atomicAdd into out
__global__ __launch_bounds__(512, 1) void fused_moe(
    const __hip_bfloat16* __restrict__ xbf, const float* __restrict__ wg,
    const float* __restrict__ wu, const float* __restrict__ wd,
    const int* __restrict__ bucket_tok, const float* __restrict__ bucket_gate,
    const int* __restrict__ count, __hip_bfloat16* __restrict__ Aws,
    float* __restrict__ out, int* __restrict__ done) {
    const int e = blockIdx.x & 63;
    const int c = blockIdx.x >> 6;
    const int tid = threadIdx.x;
    const int lane = tid & 63, w = tid >> 6;
    const int q = lane >> 4, r16 = lane & 15;

    __shared__ char smem[2 * BUFB] __attribute__((aligned(16)));
    __shared__ int base_sm;

    const int n = count[e];
    // base[e] via 64-lane shfl scan (replaces base_scan kernel)
    if (tid < 64) {
        int cv = count[tid];
        int inc = cv;
#pragma unroll
        for (int off = 1; off < 64; off <<= 1) {
            int v = __shfl_up(inc, off, 64);
            if (tid >= off) inc += v;
        }
        if (tid == e) base_sm = inc - cv;
    }
    __syncthreads();
    const int b0 = base_sm;
    if (n == 0) return;   // siblings also return; nobody waits on e

    // ================= phase 1: gateup =================
    {
        const int c0 = c * 256;
        const float* wsrc[2];
        unsigned wldso[2];
#pragma unroll
        for (int i = 0; i < 2; ++i) {
            int slot = i * 512 + tid;
            int cg = slot >> 3, kq = slot & 7;
            const float* bp = (cg < 64) ? (wg + (size_t)e * HIDDEN * INTER + c0 + cg * 4)
                                        : (wu + (size_t)e * HIDDEN * INTER + c0 + (cg - 64) * 4);
            wsrc[i] = bp + (size_t)(kq * 4) * INTER;
            wldso[i] = (unsigned)((cg * 4) * ROWB + kq * 8);
        }
        const bool xv = tid < 384;
        const int xrow = tid >> 2, xch = tid & 3;
        const unsigned xldso = (unsigned)(XOFF + xrow * ROWB + xch * 16);

        for (int m0 = 0; m0 < n; m0 += MT) {
            int px = m0 + xrow;
            int tok = (xv && px < n) ? bucket_tok[e * NTOK + px] : 0;
            const __hip_bfloat16* xp = xbf + (size_t)tok * HIDDEN + xch * 8;

            floatx4 acc[6][4];
#pragma unroll
            for (int ms = 0; ms < 6; ++ms)
#pragma unroll
                for (int s = 0; s < 4; ++s) acc[ms][s] = (floatx4){0.f, 0.f, 0.f, 0.f};

            float4 wrA[2][4], wrB[2][4];
            uint4 xrA, xrB;

            auto issueA = [&](int kt) {
#pragma unroll
                for (int i = 0; i < 2; ++i)
#pragma unroll
                    for (int j = 0; j < 4; ++j)
                        wrA[i][j] = *(const float4*)(wsrc[i] + (size_t)kt * 32 * INTER + (size_t)j * INTER);
                if (xv) xrA = *(const uint4*)(xp + kt * 32);
            };
            auto issueB = [&](int kt) {
#pragma unroll
                for (int i = 0; i < 2; ++i)
#pragma unroll
                    for (int j = 0; j < 4; ++j)
                        wrB[i][j] = *(const float4*)(wsrc[i] + (size_t)kt * 32 * INTER + (size_t)j * INTER);
                if (xv) xrB = *(const uint4*)(xp + kt * 32);
            };
            auto writeLDS = [&](char* buf, float4 (&wr_)[2][4], uint4& xr_) {
#pragma unroll
                for (int i = 0; i < 2; ++i)
#pragma unroll
                    for (int cc = 0; cc < 4; ++cc)
                        *(uint2*)(buf + wldso[i] + cc * ROWB) =
                            pack4(wr_[i][0][cc], wr_[i][1][cc], wr_[i][2][cc], wr_[i][3][cc]);
                if (xv) *(uint4*)(buf + xldso) = xr_;
            };
            auto compute = [&](const char* buf) {
                shortx8 bfr[4];
#pragma unroll
                for (int s = 0; s < 2; ++s) {
                    bfr[s]     = *(const shortx8*)(buf + ((2 * w + s) * 16 + r16) * ROWB + q * 16);
                    bfr[2 + s] = *(const shortx8*)(buf + ((256 + (2 * w + s) * 16) + r16) * ROWB + q * 16);
                }
                shortx8 afr[6];
#pragma unroll
                for (int ms = 0; ms < 6; ++ms)
                    afr[ms] = *(const shortx8*)(buf + XOFF + (ms * 16 + r16) * ROWB + q * 16);
#pragma unroll
                for (int ms = 0; ms < 6; ++ms)
#pragma unroll
                    for (int s = 0; s < 4; ++s)
                        acc[ms][s] = __builtin_amdgcn_mfma_f32_16x16x32_bf16(afr[ms], bfr[s], acc[ms][s], 0, 0, 0);
            };

            issueA(0);
            issueB(1);
            for (int kt2 = 0; kt2 < (HIDDEN / 32) / 2; ++kt2) {
                const int kt = 2 * kt2;
                writeLDS(smem, wrA, xrA);
                asm volatile("s_waitcnt lgkmcnt(0)" ::: "memory");
                __builtin_amdgcn_s_barrier();
                if (kt + 2 < HIDDEN / 32) issueA(kt + 2);
                compute(smem);
                __builtin_amdgcn_s_barrier();
                writeLDS(smem + BUFB, wrB, xrB);
                asm volatile("s_waitcnt lgkmcnt(0)" ::: "memory");
                __builtin_amdgcn_s_barrier();
                if (kt + 3 < HIDDEN / 32) issueB(kt + 3);
                compute(smem + BUFB);
                __builtin_amdgcn_s_barrier();
            }

            // epilogue: A = silu(h) * u * gate, bf16
#pragma unroll
            for (int ms = 0; ms < 6; ++ms) {
#pragma unroll
                for (int j = 0; j < 2; ++j) {
                    floatx4 h4 = acc[ms][j], u4 = acc[ms][j + 2];
#pragma unroll
                    for (int rr = 0; rr < 4; ++rr) {
                        int ml = ms * 16 + 4 * q + rr;
                        int p = m0 + ml;
                        if (p < n) {
                            float gt = bucket_gate[e * NTOK + p];
                            float hv = h4[rr];
                            float av = hv / (1.f + __expf(-hv)) * u4[rr] * gt;
                            int col = c0 + (2 * w + j) * 16 + r16;
                            Aws[(size_t)(b0 + p) * INTER + col] = __float2bfloat16(av);
                        }
                    }
                }
            }
        }
    }

    // ================= signal & wait =================
    __threadfence();
    __syncthreads();
    if (tid == 0) {
        atomicAdd(&done[e], 1);
        while (__hip_atomic_load(&done[e], __ATOMIC_ACQUIRE, __HIP_MEMORY_SCOPE_AGENT) < 4)
            __builtin_amdgcn_s_sleep(8);
    }
    __syncthreads();

    // ================= phase 2: down =================
    {
        const int c0 = c * 512;
        const float* wsrc[2];
        unsigned wldso[2];
#pragma unroll
        for (int i = 0; i < 2; ++i) {
            int slot = i * 512 + tid;
            int cg = slot >> 3, kq = slot & 7;
            wsrc[i] = wd + (size_t)e * INTER * HIDDEN + c0 + cg * 4 + (size_t)(kq * 4) * HIDDEN;
            wldso[i] = (unsigned)((cg * 4) * ROWB + kq * 8);
        }
        const bool xv = tid < 384;
        const int xrow = tid >> 2, xch = tid & 3;
        const unsigned xldso = (unsigned)(XOFF + xrow * ROWB + xch * 16);

        for (int m0 = 0; m0 < n; m0 += MT) {
            const __hip_bfloat16* ap = Aws + (size_t)(b0 + m0 + xrow) * INTER + xch * 8;

            floatx4 acc[6][4];
#pragma unroll
            for (int ms = 0; ms < 6; ++ms)
#pragma unroll
                for (int s = 0; s < 4; ++s) acc[ms][s] = (floatx4){0.f, 0.f, 0.f, 0.f};

            float4 wrA[2][4], wrB[2][4];
            uint4 arA, arB;

            auto issueA = [&](int kt) {
#pragma unroll
                for (int i = 0; i < 2; ++i)
#pragma unroll
                    for (int j = 0; j < 4; ++j)
                        wrA[i][j] = *(const float4*)(wsrc[i] + (size_t)kt * 32 * HIDDEN + (size_t)j * HIDDEN);
                if (xv) arA = *(const uint4*)(ap + kt * 32);
            };
            auto issueB = [&](int kt) {
#pragma unroll
                for (int i = 0; i < 2; ++i)
#pragma unroll
                    for (int j = 0; j < 4; ++j)
                        wrB[i][j] = *(const float4*)(wsrc[i] + (size_t)kt * 32 * HIDDEN + (size_t)j * HIDDEN);
                if (xv) arB = *(const uint4*)(ap + kt * 32);
            };
            auto writeLDS = [&](char* buf, float4 (&wr_)[2][4], uint4& ar_) {
#pragma unroll
                for (int i = 0; i < 2; ++i)
#pragma unroll
                    for (int cc = 0; cc < 4; ++cc)
                        *(uint2*)(buf + wldso[i] + cc * ROWB) =
                            pack4(wr_[i][0][cc], wr_[i][1][cc], wr_[i][2][cc], wr_[i][3][cc]);
                if (xv) *(uint4*)(buf + xldso) = ar_;
            };
            auto compute = [&](const char* buf) {
                shortx8 bfr[4];
#pragma unroll
                for (int s = 0; s < 4; ++s)
                    bfr[s] = *(const shortx8*)(buf + ((4 * w + s) * 16 + r16) * ROWB + q * 16);
                shortx8 afr[6];
#pragma unroll
                for (int ms = 0; ms < 6; ++ms)
                    afr[ms] = *(const shortx8*)(buf + XOFF + (ms * 16 + r16) * ROWB + q * 16);
#pragma unroll
                for (int ms = 0; ms < 6; ++ms)
#pragma unroll
                    for (int s = 0; s < 4; ++s)
                        acc[ms][s] = __builtin_amdgcn_mfma_f32_16x16x32_bf16(afr[ms], bfr[s], acc[ms][s], 0, 0, 0);
            };

            issueA(0);
            issueB(1);
            for (int kt2 = 0; kt2 < (INTER / 32) / 2; ++kt2) {
                const int kt = 2 * kt2;
                writeLDS(smem, wrA, arA);
                asm volatile("s_waitcnt lgkmcnt(0)" ::: "memory");
                __builtin_amdgcn_s_barrier();
                if (kt + 2 < INTER / 32) issueA(kt + 2);
                compute(smem);
                __builtin_amdgcn_s_barrier();
                writeLDS(smem + BUFB, wrB, arB);
                asm volatile("s_waitcnt lgkmcnt(0)" ::: "memory");
                __builtin_amdgcn_s_barrier();
                if (kt + 3 < INTER / 32) issueB(kt + 3);
                compute(smem + BUFB);
                __builtin_amdgcn_s_barrier();
            }

#pragma unroll
            for (int ms = 0; ms < 6; ++ms) {
#pragma unroll
                for (int rr = 0; rr < 4; ++rr) {
                    int ml = ms * 16 + 4 * q + rr;
                    int p = m0 + ml;
                    if (p < n) {
                        int tok = bucket_tok[e * NTOK + p];
                        float* orow = out + (size_t)tok * HIDDEN;
#pragma unroll
                        for (int s = 0; s < 4; ++s) {
                            int col = c0 + (4 * w + s) * 16 + r16;
                            unsafeAtomicAdd(&orow[col], acc[ms][s][rr]);
                        }
                    }
                }
            }
        }
    }
}

extern "C" void kernel_launch(void* const* d_in, const int* in_sizes, int n_in,
                              void* d_out, int out_size, void* d_ws, size_t ws_size,
                              hipStream_t stream) {
    const float* x = (const float*)d_in[0];
    const float* wr = (const float*)d_in[1];
    const float* wg = (const float*)d_in[2];
    const float* wu = (const float*)d_in[3];
    const float* wd = (const float*)d_in[4];
    float* out = (float*)d_out;

    char* ws = (char*)d_ws;
    size_t off = 0;
    auto alloc = [&](size_t bytes) {
        void* p = ws + off;
        off = (off + bytes + 255) & ~(size_t)255;
        return p;
    };
    int* topk_idx = (int*)alloc(NTOK * TOPK * sizeof(int));
    float* gates = (float*)alloc(NTOK * TOPK * sizeof(float));
    int* bucket_tok = (int*)alloc(NEXP * NTOK * sizeof(int));
    float* bucket_gate = (float*)alloc(NEXP * NTOK * sizeof(float));
    int* count = (int*)alloc(NEXP * sizeof(int));
    int* done = (int*)alloc(NEXP * sizeof(int));
    __hip_bfloat16* Aws = (__hip_bfloat16*)alloc((size_t)AWS_ROWS * INTER * sizeof(__hip_bfloat16));
    __hip_bfloat16* xbf = (__hip_bfloat16*)alloc((size_t)NTOK * HIDDEN * sizeof(__hip_bfloat16));
    (void)ws_size;

    hipMemsetAsync(d_out, 0, (size_t)NTOK * HIDDEN * sizeof(float), stream);

    router_topk_kernel<<<NTOK, 64, 0, stream>>>(x, wr, topk_idx, gates, xbf);
    build_buckets_kernel<<<NEXP, 256, 0, stream>>>(topk_idx, gates, bucket_tok, bucket_gate, count, done);
    fused_moe<<<NEXP * 4, 512, 0, stream>>>(xbf, wg, wu, wd, bucket_tok, bucket_gate,
                                            count, Aws, out, done);
}